// Round 8
// baseline (343.833 us; speedup 1.0000x reference)
//
#include <hip/hip_runtime.h>
#include <hip/hip_bf16.h>
#include <stdint.h>

typedef short bf16x8 __attribute__((ext_vector_type(8)));
typedef float f32x4 __attribute__((ext_vector_type(4)));

__device__ __forceinline__ unsigned short f2bf(float x) {
  uint32_t u = __builtin_bit_cast(uint32_t, x);
  u += 0x7FFFu + ((u >> 16) & 1u);
  return (unsigned short)(u >> 16);
}
__device__ __forceinline__ float bf2f(unsigned short u) {
  uint32_t v = ((uint32_t)u) << 16;
  return __builtin_bit_cast(float, v);
}

__device__ __forceinline__ void gl2lds16(const void* g, void* l) {
  __builtin_amdgcn_global_load_lds(
      (const __attribute__((address_space(1))) unsigned int*)g,
      (__attribute__((address_space(3))) unsigned int*)l, 16, 0, 0);
}

__global__ __launch_bounds__(256) void cast_f32_bf16_k(
    const float* __restrict__ s, unsigned short* __restrict__ d, long n) {
  long i = ((long)blockIdx.x * 256 + threadIdx.x) * 8;
  if (i >= n) return;
  float4 a = *(const float4*)(s + i);
  float4 b = *(const float4*)(s + i + 4);
  bf16x8 o;
  o[0] = (short)f2bf(a.x); o[1] = (short)f2bf(a.y);
  o[2] = (short)f2bf(a.z); o[3] = (short)f2bf(a.w);
  o[4] = (short)f2bf(b.x); o[5] = (short)f2bf(b.y);
  o[6] = (short)f2bf(b.z); o[7] = (short)f2bf(b.w);
  *(bf16x8*)(d + i) = o;
}

__global__ __launch_bounds__(256) void cast4_f32_bf16_k(
    const float* __restrict__ s0, const float* __restrict__ s1,
    const float* __restrict__ s2, const float* __restrict__ s3,
    unsigned short* __restrict__ d, long n) {
  const float* s = blockIdx.z == 0 ? s0 : blockIdx.z == 1 ? s1 : blockIdx.z == 2 ? s2 : s3;
  long i = ((long)blockIdx.x * 256 + threadIdx.x) * 8;
  if (i >= n) return;
  float4 a = *(const float4*)(s + i);
  float4 b = *(const float4*)(s + i + 4);
  bf16x8 o;
  o[0] = (short)f2bf(a.x); o[1] = (short)f2bf(a.y);
  o[2] = (short)f2bf(a.z); o[3] = (short)f2bf(a.w);
  o[4] = (short)f2bf(b.x); o[5] = (short)f2bf(b.y);
  o[6] = (short)f2bf(b.z); o[7] = (short)f2bf(b.w);
  *(bf16x8*)(d + blockIdx.z * n + i) = o;
}

// ============================================================================
// 256x256 m201-style 8-phase GEMM, TRANSPOSED OUTPUT:
//   Cfrag[m][n] = sum_k A[m][k]*B[n][k]   (A,B bf16 row-major, ldA/ldB strides)
// written transposed: dst[col*ldT + row]; fragment rows r=0..3 are consecutive
// -> each store is a contiguous ushort4/float4.
// V^T note (R7 bug fix): PV consumes vt as [D][B*S]; that IS the standard
// transposed write with ldT = B*S, so no special epilogue exists anymore.
// Loop schedule = R6 (hand-verified FIFO; 0 bank conflicts; counted vmcnt(4)
// gates on loads ~4 phases old; never drains mid-loop; setprio on MFMA).
// ============================================================================
template <typename OutT>
__global__ __launch_bounds__(512, 2) void gemm_tt(
    const unsigned short* __restrict__ A, const unsigned short* __restrict__ B,
    OutT* __restrict__ C, int K,
    long sA, long sB, long sC, int ldA, int ldB, int ldT, float alpha) {
  extern __shared__ __align__(16) char smem[];
  const int bz = blockIdx.z;
  const int gx = gridDim.x;
  const int nwg = gx * gridDim.y;  // must be %8==0
  const int idx = blockIdx.y * gx + blockIdx.x;
  const int wg = (idx & 7) * (nwg >> 3) + (idx >> 3);
  const int bm = wg / gx, bn = wg % gx;

  const int tid = threadIdx.x, lane = tid & 63, wave = tid >> 6;
  const int wm = wave >> 2, wn = wave & 3;

  const long ldAb = (long)ldA * 2, ldBb = (long)ldB * 2;
  const char* Ac = (const char*)(A + (long)bz * sA) + (long)bm * 256 * ldAb;
  const char* Bc = (const char*)(B + (long)bz * sB) + (long)bn * 256 * ldBb;
  C += (long)bz * sC;

  // staging: region = 128 rows x 128B half-tile; thread covers 2 x 16B chunks
  const int sr8 = tid >> 3;
  const int scolx = (((tid & 7) ^ ((tid >> 3) & 7)) << 4);  // pre-swizzled col

  auto stageHalf = [&](int t, int op, int h, const char* gbase, long ldb_) {
    char* reg = smem + (((((t & 1) << 1) | op) << 1 | h) << 14);
    const long ktb = (long)t << 7;
#pragma unroll
    for (int c = 0; c < 2; ++c)
      gl2lds16(gbase + (long)(h * 128 + c * 64 + sr8) * ldb_ + ktb + scolx,
               reg + c * 8192 + tid * 16);
  };

  const char* Areg[2] = { smem + ((0 << 2 | wm) << 14),
                          smem + ((1 << 2 | wm) << 14) };
  const char* Breg[2] = { smem + (((0 << 2) | 2 | (wn >> 1)) << 14),
                          smem + (((1 << 2) | 2 | (wn >> 1)) << 14) };
  const int cko[2] = { (((lane >> 4) << 4) ^ ((lane & 7) << 4)),
                       ((64 | ((lane >> 4) << 4)) ^ ((lane & 7) << 4)) };
  const int rowA0 = (lane & 15) * 128;
  const int rowB0 = ((wn & 1) * 64 + (lane & 15)) * 128;

  f32x4 acc[8][4] = {};

  // prologue: B(0), A(0), B(1) = 12 loads; drain to 4 (B(0)+A(0) landed)
  stageHalf(0, 1, 0, Bc, ldBb); stageHalf(0, 1, 1, Bc, ldBb);
  stageHalf(0, 0, 0, Ac, ldAb); stageHalf(0, 0, 1, Ac, ldAb);
  stageHalf(1, 1, 0, Bc, ldBb); stageHalf(1, 1, 1, Bc, ldBb);
  asm volatile("s_waitcnt vmcnt(4)" ::: "memory");
  __builtin_amdgcn_s_barrier();

  const int nt = K >> 6;         // even, >= 4
  const int niter = nt >> 1;
  for (int i = 0; i < niter; ++i) {
    const int u = 2 * i;
    const bool pf = (i + 1 < niter);
#pragma unroll
    for (int d = 0; d < 2; ++d) {
      bf16x8 b[4][2];
#pragma unroll
      for (int mq = 0; mq < 4; ++mq) {
        bf16x8 a[2][2];
        if (mq == 0) {
#pragma unroll
          for (int n = 0; n < 4; ++n)
#pragma unroll
            for (int kh = 0; kh < 2; ++kh)
              b[n][kh] = *(const bf16x8*)(Breg[d] + rowB0 + n * 2048 + cko[kh]);
        }
#pragma unroll
        for (int j = 0; j < 2; ++j)
#pragma unroll
          for (int kh = 0; kh < 2; ++kh)
            a[j][kh] = *(const bf16x8*)(Areg[d] + rowA0 + (mq * 2 + j) * 2048 + cko[kh]);
        // stage schedule (hand-verified FIFO)
        if (d == 0 && mq == 0) { stageHalf(u + 1, 0, 0, Ac, ldAb); stageHalf(u + 1, 0, 1, Ac, ldAb); }
        if (d == 0 && mq == 1 && pf) stageHalf(u + 2, 1, 0, Bc, ldBb);
        if (d == 0 && mq == 2 && pf) stageHalf(u + 2, 1, 1, Bc, ldBb);
        if (d == 1 && mq == 0 && pf) { stageHalf(u + 2, 0, 0, Ac, ldAb); stageHalf(u + 2, 0, 1, Ac, ldAb); }
        if (d == 1 && mq == 1 && pf) stageHalf(u + 3, 1, 0, Bc, ldBb);
        if (d == 1 && mq == 2 && pf) stageHalf(u + 3, 1, 1, Bc, ldBb);
        if (mq == 0) asm volatile("s_waitcnt lgkmcnt(8)" ::: "memory");
        __builtin_amdgcn_s_barrier();
        asm volatile("s_waitcnt lgkmcnt(0)" ::: "memory");
        __builtin_amdgcn_sched_barrier(0);
        __builtin_amdgcn_s_setprio(1);
#pragma unroll
        for (int kh = 0; kh < 2; ++kh)
#pragma unroll
          for (int j = 0; j < 2; ++j)
#pragma unroll
            for (int n = 0; n < 4; ++n)
              acc[mq * 2 + j][n] = __builtin_amdgcn_mfma_f32_16x16x32_bf16(
                  a[j][kh], b[n][kh], acc[mq * 2 + j][n], 0, 0, 0);
        __builtin_amdgcn_s_setprio(0);
        if (d == 0 && mq == 3) {
          if (pf) asm volatile("s_waitcnt vmcnt(4)" ::: "memory");
          else    asm volatile("s_waitcnt vmcnt(0)" ::: "memory");
        }
        if (d == 1 && mq == 3 && pf) asm volatile("s_waitcnt vmcnt(4)" ::: "memory");
        __builtin_amdgcn_s_barrier();
      }
    }
  }

  // epilogue: fragment layout col=lane&15, row=(lane>>4)*4+reg [m89/m91],
  // rows r=0..3 consecutive -> contiguous vector in transposed write.
  const long row0 = (long)bm * 256 + wm * 128 + (lane >> 4) * 4;
  const int col0 = bn * 256 + wn * 64 + (lane & 15);
#pragma unroll
  for (int m = 0; m < 8; ++m) {
#pragma unroll
    for (int n = 0; n < 4; ++n) {
      long row = row0 + m * 16;
      long col = col0 + n * 16;
      long base = col * (long)ldT + row;
      if constexpr (sizeof(OutT) == 2) {
        ushort4 st;
        st.x = f2bf(acc[m][n][0] * alpha); st.y = f2bf(acc[m][n][1] * alpha);
        st.z = f2bf(acc[m][n][2] * alpha); st.w = f2bf(acc[m][n][3] * alpha);
        *(ushort4*)((unsigned short*)C + base) = st;
      } else {
        float4 st;
        st.x = acc[m][n][0] * alpha; st.y = acc[m][n][1] * alpha;
        st.z = acc[m][n][2] * alpha; st.w = acc[m][n][3] * alpha;
        *(float4*)((float*)C + base) = st;
      }
    }
  }
}

// in-place row softmax on bf16 rows of length C (C == 2048, 256 thr * 8)
__global__ __launch_bounds__(256) void softmax_inplace(unsigned short* __restrict__ s, int C) {
  __shared__ float red[8];
  long row = blockIdx.x;
  unsigned short* p = s + row * (long)C;
  int tid = threadIdx.x, lane = tid & 63, w = tid >> 6;
  bf16x8 raw = *(const bf16x8*)(p + tid * 8);
  float v[8];
  float mx = -3.4e38f;
#pragma unroll
  for (int j = 0; j < 8; ++j) { v[j] = bf2f((unsigned short)raw[j]); mx = fmaxf(mx, v[j]); }
#pragma unroll
  for (int o = 32; o > 0; o >>= 1) mx = fmaxf(mx, __shfl_xor(mx, o));
  if (lane == 0) red[w] = mx;
  __syncthreads();
  mx = fmaxf(fmaxf(red[0], red[1]), fmaxf(red[2], red[3]));
  float sum = 0.f;
#pragma unroll
  for (int j = 0; j < 8; ++j) { v[j] = __expf(v[j] - mx); sum += v[j]; }
#pragma unroll
  for (int o = 32; o > 0; o >>= 1) sum += __shfl_xor(sum, o);
  if (lane == 0) red[4 + w] = sum;
  __syncthreads();
  float inv = 1.f / (red[4] + red[5] + red[6] + red[7]);
  bf16x8 o8;
#pragma unroll
  for (int j = 0; j < 8; ++j) o8[j] = (short)f2bf(v[j] * inv);
  *(bf16x8*)(p + tid * 8) = o8;
}

extern "C" void kernel_launch(void* const* d_in, const int* in_sizes, int n_in,
                              void* d_out, int out_size, void* d_ws, size_t ws_size,
                              hipStream_t stream) {
  (void)in_sizes; (void)n_in; (void)out_size; (void)ws_size;
  const float* x  = (const float*)d_in[0];
  const float* Wq = (const float*)d_in[1];
  const float* Wk = (const float*)d_in[2];
  const float* Wv = (const float*)d_in[3];
  const float* Wo = (const float*)d_in[4];
  const int B = 8, S = 2048, D = 1024;
  const long MB = 1 << 20;
  char* w = (char*)d_ws;
  unsigned short* Wqb = (unsigned short*)(w + 0 * MB);
  unsigned short* Wkb = (unsigned short*)(w + 2 * MB);
  unsigned short* Wvb = (unsigned short*)(w + 4 * MB);
  unsigned short* Wob = (unsigned short*)(w + 6 * MB);
  unsigned short* xb  = (unsigned short*)(w + 8 * MB);
  unsigned short* qb  = (unsigned short*)(w + 40 * MB);
  unsigned short* kb  = (unsigned short*)(w + 72 * MB);
  unsigned short* vt  = (unsigned short*)(w + 104 * MB); // V^T as [D][B*S] (32MB)
  unsigned short* wb  = xb;  // x dead after projections
  unsigned short* attn = (unsigned short*)d_out;
  float* out = (float*)d_out;

  long nx = (long)B * S * D;
  long nw = (long)D * D;

  const int LDSB = 131072;
  hipFuncSetAttribute((const void*)gemm_tt<unsigned short>,
                      hipFuncAttributeMaxDynamicSharedMemorySize, LDSB);
  hipFuncSetAttribute((const void*)gemm_tt<float>,
                      hipFuncAttributeMaxDynamicSharedMemorySize, LDSB);

  cast_f32_bf16_k<<<(int)(nx / 2048), 256, 0, stream>>>(x, xb, nx);
  dim3 gW((int)(nw / 2048), 1, 4);
  cast4_f32_bf16_k<<<gW, 256, 0, stream>>>(Wq, Wk, Wv, Wo, Wqb, nw);

  // Q-proj (swapped): C = Wq @ x^T -> transposed-write = q [16384][1024]
  dim3 gQ(64, 4, 1);
  gemm_tt<unsigned short><<<gQ, 512, LDSB, stream>>>(
      Wqb, xb, qb, D, 0, 0, 0, D, D, D, 1.f);
  // K-proj (swapped)
  gemm_tt<unsigned short><<<gQ, 512, LDSB, stream>>>(
      Wkb, xb, kb, D, 0, 0, 0, D, D, D, 1.f);
  // V-proj (unswapped): Cfrag[xrow][d] -> transposed-write ldT=B*S gives
  // vt[d*16384 + xrow] = [D][B*S]  (exactly what PV consumes)
  dim3 gV(4, 64, 1);
  gemm_tt<unsigned short><<<gV, 512, LDSB, stream>>>(
      xb, Wvb, vt, D, 0, 0, 0, D, D, B * S, 1.f);

  // scores (swapped): C = k @ q^T = scores^T -> transposed-write = scores row-major
  dim3 gS(8, 8, B);
  gemm_tt<unsigned short><<<gS, 512, LDSB, stream>>>(
      kb, qb, attn, D, (long)S * D, (long)S * D, (long)S * S, D, D, S, 0.03125f);

  softmax_inplace<<<B * S, 256, 0, stream>>>(attn, S);

  // PV (swapped): A = vt [D][B*S] (batch col-offset S), B = attn;
  // Cfrag[d][s] -> transposed-write = wb [16384][1024] row-major
  dim3 gPV(8, 4, B);
  gemm_tt<unsigned short><<<gPV, 512, LDSB, stream>>>(
      vt, attn, wb, S, (long)S, (long)S * S, (long)S * D, B * S, S, D, 1.f);

  // out-proj (swapped, fp32): C = Wo @ wb^T -> transposed float4-write = out
  dim3 gO(64, 4, 1);
  gemm_tt<float><<<gO, 512, LDSB, stream>>>(
      Wob, wb, out, D, 0, 0, 0, D, D, D, 1.f);
}

// Round 10
// 341.538 us; speedup vs baseline: 1.0067x; 1.0067x over previous
//
#include <hip/hip_runtime.h>
#include <hip/hip_bf16.h>
#include <stdint.h>

typedef short bf16x8 __attribute__((ext_vector_type(8)));
typedef float f32x4 __attribute__((ext_vector_type(4)));

__device__ __forceinline__ unsigned short f2bf(float x) {
  uint32_t u = __builtin_bit_cast(uint32_t, x);
  u += 0x7FFFu + ((u >> 16) & 1u);
  return (unsigned short)(u >> 16);
}
__device__ __forceinline__ float bf2f(unsigned short u) {
  uint32_t v = ((uint32_t)u) << 16;
  return __builtin_bit_cast(float, v);
}

__device__ __forceinline__ void gl2lds16(const void* g, void* l) {
  __builtin_amdgcn_global_load_lds(
      (const __attribute__((address_space(1))) unsigned int*)g,
      (__attribute__((address_space(3))) unsigned int*)l, 16, 0, 0);
}

__global__ __launch_bounds__(256) void cast_f32_bf16_k(
    const float* __restrict__ s, unsigned short* __restrict__ d, long n) {
  long i = ((long)blockIdx.x * 256 + threadIdx.x) * 8;
  if (i >= n) return;
  float4 a = *(const float4*)(s + i);
  float4 b = *(const float4*)(s + i + 4);
  bf16x8 o;
  o[0] = (short)f2bf(a.x); o[1] = (short)f2bf(a.y);
  o[2] = (short)f2bf(a.z); o[3] = (short)f2bf(a.w);
  o[4] = (short)f2bf(b.x); o[5] = (short)f2bf(b.y);
  o[6] = (short)f2bf(b.z); o[7] = (short)f2bf(b.w);
  *(bf16x8*)(d + i) = o;
}

__global__ __launch_bounds__(256) void cast4_f32_bf16_k(
    const float* __restrict__ s0, const float* __restrict__ s1,
    const float* __restrict__ s2, const float* __restrict__ s3,
    unsigned short* __restrict__ d, long n) {
  const float* s = blockIdx.z == 0 ? s0 : blockIdx.z == 1 ? s1 : blockIdx.z == 2 ? s2 : s3;
  long i = ((long)blockIdx.x * 256 + threadIdx.x) * 8;
  if (i >= n) return;
  float4 a = *(const float4*)(s + i);
  float4 b = *(const float4*)(s + i + 4);
  bf16x8 o;
  o[0] = (short)f2bf(a.x); o[1] = (short)f2bf(a.y);
  o[2] = (short)f2bf(a.z); o[3] = (short)f2bf(a.w);
  o[4] = (short)f2bf(b.x); o[5] = (short)f2bf(b.y);
  o[6] = (short)f2bf(b.z); o[7] = (short)f2bf(b.w);
  *(bf16x8*)(d + blockIdx.z * n + i) = o;
}

// ============================================================================
// 256x256 pipelined GEMM, TRANSPOSED OUTPUT:
//   Cfrag[m][n] = sum_k A[m][k]*B[n][k]; written dst[col*ldT + row] (coalesced
//   ushort4/float4: fragment rows r=0..3 contiguous).
// Cross-phase LDS-read pipelining with COUNTED lgkmcnt (kh-outer, 8 phases of
// 8 MFMA per tile; each phase issues next phase's 2 A-reads then lgkmcnt(2)).
// R10 fix vs R9: B-next staging moved kh0->kh1. R9 staged B(u+2) into the
// SAME region (buf u&1, op1) at (kh0,mq1/2) while the kh1 B-reload reads it
// at (kh0,mq3) -> HBM write could land before the read (WAR race, absmax
// 0.33). Now staged at (kh1,mq1/2): the reload's reads are drained by
// lgkmcnt(2) at (kh1,mq0) in EVERY wave + barrier before the stores issue.
// vm FIFO per d-tile unchanged (A-stage 4 loads then B-stage 4), so gates:
//   end-d0: pf ? vmcnt(4) : vmcnt(0)   [drains B(u+1)+A(u+1)]
//   end-d1: pf ? vmcnt(4) : none       [drains B(u+2)+A(u+2)]
// lgkm ledger per phase (hand-verified): 6->8(2)->4(2)->4(2)->4(2)+b4->
//   8(2)->4(2)->4(2)->4(0).
// ============================================================================
template <typename OutT>
__global__ __launch_bounds__(512, 2) void gemm_tt(
    const unsigned short* __restrict__ A, const unsigned short* __restrict__ B,
    OutT* __restrict__ C, int K,
    long sA, long sB, long sC, int ldA, int ldB, int ldT, float alpha) {
  extern __shared__ __align__(16) char smem[];
  const int bz = blockIdx.z;
  const int gx = gridDim.x;
  const int nwg = gx * gridDim.y;  // must be %8==0
  const int idx = blockIdx.y * gx + blockIdx.x;
  const int wg = (idx & 7) * (nwg >> 3) + (idx >> 3);
  const int bm = wg / gx, bn = wg % gx;

  const int tid = threadIdx.x, lane = tid & 63, wave = tid >> 6;
  const int wm = wave >> 2, wn = wave & 3;

  const long ldAb = (long)ldA * 2, ldBb = (long)ldB * 2;
  const char* Ac = (const char*)(A + (long)bz * sA) + (long)bm * 256 * ldAb;
  const char* Bc = (const char*)(B + (long)bz * sB) + (long)bn * 256 * ldBb;
  C += (long)bz * sC;

  const int sr8 = tid >> 3;
  const int scolx = (((tid & 7) ^ ((tid >> 3) & 7)) << 4);  // pre-swizzled col

  auto stageHalf = [&](int t, int op, int h, const char* gbase, long ldb_) {
    char* reg = smem + (((((t & 1) << 1) | op) << 1 | h) << 14);
    const long ktb = (long)t << 7;
#pragma unroll
    for (int c = 0; c < 2; ++c)
      gl2lds16(gbase + (long)(h * 128 + c * 64 + sr8) * ldb_ + ktb + scolx,
               reg + c * 8192 + tid * 16);
  };

  const char* Areg[2] = { smem + ((0 << 2 | wm) << 14),
                          smem + ((1 << 2 | wm) << 14) };
  const char* Breg[2] = { smem + (((0 << 2) | 2 | (wn >> 1)) << 14),
                          smem + (((1 << 2) | 2 | (wn >> 1)) << 14) };
  const int cko[2] = { (((lane >> 4) << 4) ^ ((lane & 7) << 4)),
                       ((64 | ((lane >> 4) << 4)) ^ ((lane & 7) << 4)) };
  const int rowA0 = (lane & 15) * 128;
  const int rowB0 = ((wn & 1) * 64 + (lane & 15)) * 128;

  f32x4 acc[8][4] = {};

  // prologue: B(0), A(0), B(1) = 12 loads; drain to 4 (B(0)+A(0) landed)
  stageHalf(0, 1, 0, Bc, ldBb); stageHalf(0, 1, 1, Bc, ldBb);
  stageHalf(0, 0, 0, Ac, ldAb); stageHalf(0, 0, 1, Ac, ldAb);
  stageHalf(1, 1, 0, Bc, ldBb); stageHalf(1, 1, 1, Bc, ldBb);
  asm volatile("s_waitcnt vmcnt(4)" ::: "memory");
  __builtin_amdgcn_s_barrier();

  const int nt = K >> 6;         // even, >= 4
  const int niter = nt >> 1;
  for (int i = 0; i < niter; ++i) {
    const int u = 2 * i;
    const bool pf = (i + 1 < niter);
#pragma unroll
    for (int d = 0; d < 2; ++d) {
      bf16x8 b[4], a0[2], a1[2];
      // pre-tile: B(kh0) 4 + A(mq0,kh0) 2   [6 outstanding]
#pragma unroll
      for (int n = 0; n < 4; ++n)
        b[n] = *(const bf16x8*)(Breg[d] + rowB0 + n * 2048 + cko[0]);
#pragma unroll
      for (int j = 0; j < 2; ++j)
        a0[j] = *(const bf16x8*)(Areg[d] + rowA0 + j * 2048 + cko[0]);
#pragma unroll
      for (int kh = 0; kh < 2; ++kh) {
#pragma unroll
        for (int mq = 0; mq < 4; ++mq) {
          // stage schedule: A-next at kh0/mq0; B-next at kh1/mq1+mq2
          // (B staging AFTER the kh1 B-reload of this region is drained!)
          if (kh == 0 && mq == 0) {
            if (d == 0) { stageHalf(u+1,0,0,Ac,ldAb); stageHalf(u+1,0,1,Ac,ldAb); }
            else if (pf) { stageHalf(u+2,0,0,Ac,ldAb); stageHalf(u+2,0,1,Ac,ldAb); }
          }
          if (kh == 1 && pf) {
            if (d == 0 && mq == 1) stageHalf(u+2,1,0,Bc,ldBb);
            if (d == 0 && mq == 2) stageHalf(u+2,1,1,Bc,ldBb);
            if (d == 1 && mq == 1) stageHalf(u+3,1,0,Bc,ldBb);
            if (d == 1 && mq == 2) stageHalf(u+3,1,1,Bc,ldBb);
          }
          bf16x8* cur = (mq & 1) ? a1 : a0;   // compile-time after unroll
          bf16x8* nxt = (mq & 1) ? a0 : a1;
          if (mq < 3) {
#pragma unroll
            for (int j = 0; j < 2; ++j)
              nxt[j] = *(const bf16x8*)(Areg[d] + rowA0 + ((mq+1)*2 + j) * 2048 + cko[kh]);
            asm volatile("s_waitcnt lgkmcnt(2)" ::: "memory");
          } else if (kh == 0) {
            // prefetch first A-quad of kh1 before waiting
#pragma unroll
            for (int j = 0; j < 2; ++j)
              nxt[j] = *(const bf16x8*)(Areg[d] + rowA0 + j * 2048 + cko[1]);
            asm volatile("s_waitcnt lgkmcnt(2)" ::: "memory");
          } else {
            asm volatile("s_waitcnt lgkmcnt(0)" ::: "memory");
          }
          __builtin_amdgcn_sched_barrier(0);
          __builtin_amdgcn_s_setprio(1);
#pragma unroll
          for (int j = 0; j < 2; ++j)
#pragma unroll
            for (int n = 0; n < 4; ++n)
              acc[mq*2+j][n] = __builtin_amdgcn_mfma_f32_16x16x32_bf16(
                  cur[j], b[n], acc[mq*2+j][n], 0, 0, 0);
          __builtin_amdgcn_s_setprio(0);
          if (kh == 0 && mq == 3) {
            // reload B for kh1 (before any staging overwrites this region)
#pragma unroll
            for (int n = 0; n < 4; ++n)
              b[n] = *(const bf16x8*)(Breg[d] + rowB0 + n * 2048 + cko[1]);
          }
          if (kh == 1 && mq == 3) {  // vm gates (FIFO order unchanged vs R8)
            if (d == 0) {
              if (pf) asm volatile("s_waitcnt vmcnt(4)" ::: "memory");
              else    asm volatile("s_waitcnt vmcnt(0)" ::: "memory");
            } else if (pf) {
              asm volatile("s_waitcnt vmcnt(4)" ::: "memory");
            }
          }
          __builtin_amdgcn_s_barrier();
        }
      }
    }
  }

  // epilogue: fragment layout col=lane&15, row=(lane>>4)*4+reg [m89/m91],
  // rows r=0..3 consecutive -> contiguous vector in transposed write.
  const long row0 = (long)bm * 256 + wm * 128 + (lane >> 4) * 4;
  const int col0 = bn * 256 + wn * 64 + (lane & 15);
#pragma unroll
  for (int m = 0; m < 8; ++m) {
#pragma unroll
    for (int n = 0; n < 4; ++n) {
      long row = row0 + m * 16;
      long col = col0 + n * 16;
      long base = col * (long)ldT + row;
      if constexpr (sizeof(OutT) == 2) {
        ushort4 st;
        st.x = f2bf(acc[m][n][0] * alpha); st.y = f2bf(acc[m][n][1] * alpha);
        st.z = f2bf(acc[m][n][2] * alpha); st.w = f2bf(acc[m][n][3] * alpha);
        *(ushort4*)((unsigned short*)C + base) = st;
      } else {
        float4 st;
        st.x = acc[m][n][0] * alpha; st.y = acc[m][n][1] * alpha;
        st.z = acc[m][n][2] * alpha; st.w = acc[m][n][3] * alpha;
        *(float4*)((float*)C + base) = st;
      }
    }
  }
}

// in-place row softmax on bf16 rows of length C (C == 2048, 256 thr * 8)
__global__ __launch_bounds__(256) void softmax_inplace(unsigned short* __restrict__ s, int C) {
  __shared__ float red[8];
  long row = blockIdx.x;
  unsigned short* p = s + row * (long)C;
  int tid = threadIdx.x, lane = tid & 63, w = tid >> 6;
  bf16x8 raw = *(const bf16x8*)(p + tid * 8);
  float v[8];
  float mx = -3.4e38f;
#pragma unroll
  for (int j = 0; j < 8; ++j) { v[j] = bf2f((unsigned short)raw[j]); mx = fmaxf(mx, v[j]); }
#pragma unroll
  for (int o = 32; o > 0; o >>= 1) mx = fmaxf(mx, __shfl_xor(mx, o));
  if (lane == 0) red[w] = mx;
  __syncthreads();
  mx = fmaxf(fmaxf(red[0], red[1]), fmaxf(red[2], red[3]));
  float sum = 0.f;
#pragma unroll
  for (int j = 0; j < 8; ++j) { v[j] = __expf(v[j] - mx); sum += v[j]; }
#pragma unroll
  for (int o = 32; o > 0; o >>= 1) sum += __shfl_xor(sum, o);
  if (lane == 0) red[4 + w] = sum;
  __syncthreads();
  float inv = 1.f / (red[4] + red[5] + red[6] + red[7]);
  bf16x8 o8;
#pragma unroll
  for (int j = 0; j < 8; ++j) o8[j] = (short)f2bf(v[j] * inv);
  *(bf16x8*)(p + tid * 8) = o8;
}

extern "C" void kernel_launch(void* const* d_in, const int* in_sizes, int n_in,
                              void* d_out, int out_size, void* d_ws, size_t ws_size,
                              hipStream_t stream) {
  (void)in_sizes; (void)n_in; (void)out_size; (void)ws_size;
  const float* x  = (const float*)d_in[0];
  const float* Wq = (const float*)d_in[1];
  const float* Wk = (const float*)d_in[2];
  const float* Wv = (const float*)d_in[3];
  const float* Wo = (const float*)d_in[4];
  const int B = 8, S = 2048, D = 1024;
  const long MB = 1 << 20;
  char* w = (char*)d_ws;
  unsigned short* Wqb = (unsigned short*)(w + 0 * MB);
  unsigned short* Wkb = (unsigned short*)(w + 2 * MB);
  unsigned short* Wvb = (unsigned short*)(w + 4 * MB);
  unsigned short* Wob = (unsigned short*)(w + 6 * MB);
  unsigned short* xb  = (unsigned short*)(w + 8 * MB);
  unsigned short* qb  = (unsigned short*)(w + 40 * MB);
  unsigned short* kb  = (unsigned short*)(w + 72 * MB);
  unsigned short* vt  = (unsigned short*)(w + 104 * MB); // V^T as [D][B*S] (32MB)
  unsigned short* wb  = xb;  // x dead after projections
  unsigned short* attn = (unsigned short*)d_out;
  float* out = (float*)d_out;

  long nx = (long)B * S * D;
  long nw = (long)D * D;

  const int LDSB = 131072;
  hipFuncSetAttribute((const void*)gemm_tt<unsigned short>,
                      hipFuncAttributeMaxDynamicSharedMemorySize, LDSB);
  hipFuncSetAttribute((const void*)gemm_tt<float>,
                      hipFuncAttributeMaxDynamicSharedMemorySize, LDSB);

  cast_f32_bf16_k<<<(int)(nx / 2048), 256, 0, stream>>>(x, xb, nx);
  dim3 gW((int)(nw / 2048), 1, 4);
  cast4_f32_bf16_k<<<gW, 256, 0, stream>>>(Wq, Wk, Wv, Wo, Wqb, nw);

  // Q-proj (swapped): C = Wq @ x^T -> transposed-write = q [16384][1024]
  dim3 gQ(64, 4, 1);
  gemm_tt<unsigned short><<<gQ, 512, LDSB, stream>>>(
      Wqb, xb, qb, D, 0, 0, 0, D, D, D, 1.f);
  // K-proj (swapped)
  gemm_tt<unsigned short><<<gQ, 512, LDSB, stream>>>(
      Wkb, xb, kb, D, 0, 0, 0, D, D, D, 1.f);
  // V-proj (unswapped): Cfrag[xrow][d] -> transposed-write ldT=B*S gives
  // vt[d*16384 + xrow] = [D][B*S]  (exactly what PV consumes)
  dim3 gV(4, 64, 1);
  gemm_tt<unsigned short><<<gV, 512, LDSB, stream>>>(
      xb, Wvb, vt, D, 0, 0, 0, D, D, B * S, 1.f);

  // scores (swapped): C = k @ q^T = scores^T -> transposed-write = scores row-major
  dim3 gS(8, 8, B);
  gemm_tt<unsigned short><<<gS, 512, LDSB, stream>>>(
      kb, qb, attn, D, (long)S * D, (long)S * D, (long)S * S, D, D, S, 0.03125f);

  softmax_inplace<<<B * S, 256, 0, stream>>>(attn, S);

  // PV (swapped): A = vt [D][B*S] (batch col-offset S), B = attn;
  // Cfrag[d][s] -> transposed-write = wb [16384][1024] row-major
  dim3 gPV(8, 4, B);
  gemm_tt<unsigned short><<<gPV, 512, LDSB, stream>>>(
      vt, attn, wb, S, (long)S, (long)S * S, (long)S * D, B * S, S, D, 1.f);

  // out-proj (swapped, fp32): C = Wo @ wb^T -> transposed float4-write = out
  dim3 gO(64, 4, 1);
  gemm_tt<float><<<gO, 512, LDSB, stream>>>(
      Wob, wb, out, D, 0, 0, 0, D, D, D, 1.f);
}